// Round 3
// baseline (543.673 us; speedup 1.0000x reference)
//
#include <hip/hip_runtime.h>

// Problem constants
constexpr int BB = 2;        // batch
constexpr int CM = 96;       // d_model
constexpr int CI = 192;      // d_inner
constexpr int NPIX = 128 * 128;   // 16384
constexpr int DS = 16;            // d_state
constexpr int DC = 4 * CI;        // 768

// workspace layout (floats). Reuse: ypB overlays x1pre (dead after K2),
// yt overlays x1 (dead after K4). Total = 25,690,496 floats ~= 103 MB.
constexpr size_t OFF_X1PRE = 0;
constexpr size_t OFF_X1    = 6291456;
constexpr size_t OFF_X1T   = 12582912;
constexpr size_t OFF_XP    = 18874368;
constexpr size_t OFF_YPA   = 19398656;
constexpr size_t OFF_YPB   = 0;          // alias x1pre
constexpr size_t OFF_YT    = 6291456;    // alias x1
constexpr size_t OFF_GXS   = 25690112;

__device__ __forceinline__ float frcp(float x) { return __builtin_amdgcn_rcpf(x); }
__device__ __forceinline__ float sigm(float x) { return frcp(1.f + __expf(-x)); }

// ---------------------------------------------------------------------------
// K1: x1_pre = conv1x1(x, w_in)   (B,96,H,W) -> (B,192,H,W)
__global__ __launch_bounds__(256) void k1_conv_in(const float* __restrict__ x,
                                                  const float* __restrict__ w_in,
                                                  float* __restrict__ x1pre) {
    __shared__ float xs[16][128];
    __shared__ float wsh[16][32];
    int pt = blockIdx.x;
    int b = pt >> 7;
    int pxb = (pt & 127) * 128;
    int cb = blockIdx.y * 32;
    int tid = threadIdx.x;
    int cl0 = (tid >> 5) * 4;
    int px0 = (tid & 31) * 4;
    float acc[4][4];
#pragma unroll
    for (int i = 0; i < 4; i++)
#pragma unroll
        for (int j = 0; j < 4; j++) acc[i][j] = 0.f;

    for (int m0 = 0; m0 < 96; m0 += 16) {
        {
            int e = tid * 8;
            int ml = e >> 7, pp = e & 127;
            const float* src = &x[((size_t)(b * CM + m0 + ml)) * NPIX + pxb + pp];
            float4 v0 = *(const float4*)(src);
            float4 v1 = *(const float4*)(src + 4);
            *(float4*)&xs[ml][pp] = v0;
            *(float4*)&xs[ml][pp + 4] = v1;
        }
        if (tid < 128) {
            int cl = tid >> 2, mq = (tid & 3) * 4;
            float4 v = *(const float4*)&w_in[(size_t)(cb + cl) * CM + m0 + mq];
            wsh[mq + 0][cl] = v.x; wsh[mq + 1][cl] = v.y;
            wsh[mq + 2][cl] = v.z; wsh[mq + 3][cl] = v.w;
        }
        __syncthreads();
#pragma unroll
        for (int m = 0; m < 16; m++) {
            float4 wv = *(const float4*)&wsh[m][cl0];
            float4 xv = *(const float4*)&xs[m][px0];
            float wr[4] = {wv.x, wv.y, wv.z, wv.w};
            float xr[4] = {xv.x, xv.y, xv.z, xv.w};
#pragma unroll
            for (int i = 0; i < 4; i++)
#pragma unroll
                for (int j = 0; j < 4; j++) acc[i][j] += wr[i] * xr[j];
        }
        __syncthreads();
    }
#pragma unroll
    for (int i = 0; i < 4; i++) {
        float4 v = {acc[i][0], acc[i][1], acc[i][2], acc[i][3]};
        *(float4*)&x1pre[((size_t)(b * CI + cb + cl0 + i)) * NPIX + pxb + px0] = v;
    }
}

// ---------------------------------------------------------------------------
// K2: x1 = dwconv3x3(x1_pre)+b, writes BOTH x1 [h][w] and x1T [w][h].
// grid = 384 planes x 4 tiles(64x64); 256 threads.
__global__ __launch_bounds__(256) void k2_dwconv(const float* __restrict__ x1pre,
                                                 const float* __restrict__ w_dw,
                                                 const float* __restrict__ b_dw,
                                                 float* __restrict__ x1,
                                                 float* __restrict__ x1T) {
    __shared__ float inT[66][67];    // 17.7 KB
    __shared__ float outT[64][65];   // 16.6 KB
    int blk = blockIdx.x;
    int bc = blk >> 2;
    int tile = blk & 3;
    int h0 = (tile >> 1) * 64, w0 = (tile & 1) * 64;
    int c = bc % CI;
    const float* src = x1pre + (size_t)bc * NPIX;
    int tid = threadIdx.x;
    for (int idx = tid; idx < 66 * 66; idx += 256) {
        int r = idx / 66, cl = idx - r * 66;
        int hh = h0 - 1 + r, ww = w0 - 1 + cl;
        float v = 0.f;
        if ((unsigned)hh < 128u && (unsigned)ww < 128u) v = src[hh * 128 + ww];
        inT[r][cl] = v;
    }
    float w00 = w_dw[c * 9 + 0], w01 = w_dw[c * 9 + 1], w02 = w_dw[c * 9 + 2];
    float w10 = w_dw[c * 9 + 3], w11 = w_dw[c * 9 + 4], w12 = w_dw[c * 9 + 5];
    float w20 = w_dw[c * 9 + 6], w21 = w_dw[c * 9 + 7], w22 = w_dw[c * 9 + 8];
    float bias = b_dw[c];
    __syncthreads();
    int cl = tid & 63, r0 = tid >> 6;
#pragma unroll 4
    for (int k = 0; k < 16; k++) {
        int r = k * 4 + r0;
        float s = w00 * inT[r][cl]     + w01 * inT[r][cl + 1]     + w02 * inT[r][cl + 2]
                + w10 * inT[r + 1][cl] + w11 * inT[r + 1][cl + 1] + w12 * inT[r + 1][cl + 2]
                + w20 * inT[r + 2][cl] + w21 * inT[r + 2][cl + 1] + w22 * inT[r + 2][cl + 2]
                + bias;
        x1[(size_t)bc * NPIX + (h0 + r) * 128 + w0 + cl] = s;
        outT[r][cl] = s;
    }
    __syncthreads();
#pragma unroll 4
    for (int k = 0; k < 16; k++) {
        int r = k * 4 + r0;
        x1T[(size_t)bc * NPIX + (w0 + r) * 128 + h0 + cl] = outT[cl][r];
    }
}

// ---------------------------------------------------------------------------
// K3: xp = conv1x1(x1, w_xdown) stored TRANSPOSED as (b, w, h, 16)
__global__ __launch_bounds__(256) void k3_xp(const float* __restrict__ x1,
                                             const float* __restrict__ w_xdown,
                                             float* __restrict__ xp) {
    __shared__ float wsh[DS * CI];
    __shared__ float ph[DS][128];
    int blk = blockIdx.x;
    int b = blk >> 7, t = blk & 127;     // t = h-row index
    int tid = threadIdx.x;
    for (int e = tid * 4; e < DS * CI; e += 1024) {
        *(float4*)&wsh[e] = *(const float4*)&w_xdown[e];
    }
    __syncthreads();
    int i = tid & 127;                   // i = w index
    int half = tid >> 7;
    int c0 = half * 96;
    float acc[DS];
#pragma unroll
    for (int s = 0; s < DS; s++) acc[s] = 0.f;
    const float* xbase = x1 + ((size_t)b * CI + c0) * NPIX + t * 128 + i;
#pragma unroll 4
    for (int c = 0; c < 96; c++) {
        float v = xbase[(size_t)c * NPIX];
#pragma unroll
        for (int s = 0; s < DS; s++) acc[s] += wsh[s * CI + c0 + c] * v;
    }
    if (half == 1) {
#pragma unroll
        for (int s = 0; s < DS; s++) ph[s][i] = acc[s];
    }
    __syncthreads();
    if (half == 0) {
        float out[DS];
#pragma unroll
        for (int s = 0; s < DS; s++) out[s] = acc[s] + ph[s][i];
        float4* dst = (float4*)&xp[(((size_t)b * 128 + i) * 128 + t) * DS];
#pragma unroll
        for (int q = 0; q < 4; q++) dst[q] = *(float4*)&out[q * 4];
    }
}

// ---------------------------------------------------------------------------
// K4: fused gate-compute + tridiagonal scan, dir-PAIR per block.
// grid = 768 = (b*CI + c)*2 + parity; parity 0 -> dirs {0,2} (read x1T),
// parity 1 -> dirs {1,3} (read x1). 256 thr = 4 waves: (dir-local dl, row-half).
// 1 row/lane; seam h[63]<->h[64] via LDS; pair-merge via ycol; one barrier/step.
__global__ __launch_bounds__(256, 3) void k4_scan(
        const float* __restrict__ x1, const float* __restrict__ x1T,
        const float* __restrict__ xp,
        const float* __restrict__ w_wup, const float* __restrict__ w_lup,
        const float* __restrict__ w_uup, const float* __restrict__ w_ddown,
        const float* __restrict__ w_m,
        float* __restrict__ ypA, float* __restrict__ ypB) {
    __shared__ float xps[2][128 * 17];   // 17.4 KB, pad 17 -> conflict-free b128
    __shared__ float ycol[2][2][128];    // 4 KB
    __shared__ float seam[2][2][2];      // [buf][dl][0]=h63, [1]=h64
    int blk = blockIdx.x;
    int parity = blk & 1;
    int bc = blk >> 1;
    int c = bc % CI;
    int b = bc / CI;
    int tid = threadIdx.x;
    int dl = tid >> 7;
    int half = (tid >> 6) & 1;
    int l = tid & 63;
    int i = half * 64 + l;
    int dir = __builtin_amdgcn_readfirstlane(parity + 2 * dl);
    const float* xsrc = (parity ? x1 : x1T) + (size_t)bc * NPIX;
    float* yp = (parity ? ypB : ypA) + (size_t)bc * NPIX;

    int q = dir * CI + c;
    float wm = w_m[dir];
    float wGl[DS], wGm[DS], wGr[DS], wL[DS], wU[DS], wD[DS];
#pragma unroll
    for (int j = 0; j < DS; j++) {
        wGl[j] = w_wup[(size_t)q * DS + j];
        wGm[j] = w_wup[(size_t)(DC + q) * DS + j];
        wGr[j] = w_wup[(size_t)(2 * DC + q) * DS + j];
        wL[j]  = w_lup[(size_t)q * DS + j];
        wU[j]  = w_uup[(size_t)q * DS + j] * wm;
        wD[j]  = w_ddown[(size_t)q * DS + j] * wm;
    }
    if (tid < 8) ((float*)seam)[tid] = 0.f;
    // stage xp row 0 (2048 floats, 8/thread) into xps[0]
    const float* xprow0 = xp + (size_t)b * 128 * 2048;
    {
        float4 a = *(const float4*)&xprow0[tid * 8];
        float4 v = *(const float4*)&xprow0[tid * 8 + 4];
        int ii = tid >> 1, s0 = (tid & 1) * 8;
        *(float4*)&xps[0][ii * 17 + s0] = a;
        *(float4*)&xps[0][ii * 17 + s0 + 4] = v;
    }
    __syncthreads();

    float h = 0.f;
    for (int t = 0; t < 128; t++) {
        int buf = t & 1;
        float4 pre0, pre1;
        if (t < 127) {
            const float* srcrow = xprow0 + (size_t)(t + 1) * 2048;
            pre0 = *(const float4*)&srcrow[tid * 8];
            pre1 = *(const float4*)&srcrow[tid * 8 + 4];
        }
        int tt = dl ? (127 - t) : t;
        float X = xsrc[tt * 128 + i];
        // gate vector from LDS
        const float* g = &xps[buf][i * 17];
        float4 q0 = *(const float4*)&g[0];
        float4 q1 = *(const float4*)&g[4];
        float4 q2 = *(const float4*)&g[8];
        float4 q3 = *(const float4*)&g[12];
        float xv[DS] = {q0.x, q0.y, q0.z, q0.w, q1.x, q1.y, q1.z, q1.w,
                        q2.x, q2.y, q2.z, q2.w, q3.x, q3.y, q3.z, q3.w};
        float aGl = 0.f, aGm = 0.f, aGr = 0.f, aL = 0.f, aU = 0.f, aD = 0.f;
#pragma unroll
        for (int j = 0; j < DS; j++) {
            float xa = xv[j];
            aGl += wGl[j] * xa; aGm += wGm[j] * xa; aGr += wGr[j] * xa;
            aL  += wL[j] * xa;  aU  += wU[j] * xa;  aD  += wD[j] * xa;
        }
        float gl = sigm(aGl), gm = sigm(aGm), gr = sigm(aGr);
        float ss = (i == 0) ? (gm + gr) : (i == 127) ? (gl + gm) : (gl + gm + gr);
        float inv = frcp(fmaxf(ss, 1e-7f));
        float up = __shfl_up(h, 1);
        if (l == 0) up = half ? seam[buf ^ 1][dl][0] : 0.f;
        float dn = __shfl_down(h, 1);
        if (l == 63) dn = half ? 0.f : seam[buf ^ 1][dl][1];
        h = aL * X + inv * (gl * up + gm * h + gr * dn);
        ycol[buf][dl][i] = h * aU + X * aD;
        if (half == 0 && l == 63) seam[buf][dl][0] = h;
        if (half == 1 && l == 0)  seam[buf][dl][1] = h;
        if (t < 127) {
            int ii = tid >> 1, s0 = (tid & 1) * 8;
            *(float4*)&xps[buf ^ 1][ii * 17 + s0] = pre0;
            *(float4*)&xps[buf ^ 1][ii * 17 + s0 + 4] = pre1;
        }
        __syncthreads();
        if (tid < 128) {
            yp[t * 128 + tid] = ycol[buf][0][tid] + ycol[buf][1][tid];
        }
    }
}

// ---------------------------------------------------------------------------
// K5: merge dir-pair partials + LayerNorm over channels -> yt, + per-(b,c) ssq
__global__ __launch_bounds__(256) void k5_ln(const float* __restrict__ ypA,
                                             const float* __restrict__ ypB,
                                             const float* __restrict__ ln_w,
                                             const float* __restrict__ ln_b,
                                             float* __restrict__ yt,
                                             float* __restrict__ gxs) {
    __shared__ float red[8][64];
    int blk = blockIdx.x;
    int b = blk >> 8;
    int pxb = (blk & 255) * 64;
    int tid = threadIdx.x;
    int pl = tid & 63, cp = tid >> 6;
    int c0 = cp * 48;
    size_t base = ((size_t)b * CI + c0) * NPIX + pxb + pl;
    float val[48];
    float sum = 0.f, ssq = 0.f;
#pragma unroll
    for (int j = 0; j < 48; j++) {
        float v = ypA[base + (size_t)j * NPIX] + ypB[base + (size_t)j * NPIX];
        val[j] = v;
        sum += v; ssq += v * v;
    }
    red[cp][pl] = sum; red[4 + cp][pl] = ssq;
    __syncthreads();
    float s4 = red[0][pl] + red[1][pl] + red[2][pl] + red[3][pl];
    float q4 = red[4][pl] + red[5][pl] + red[6][pl] + red[7][pl];
    float mu = s4 * (1.f / 192.f);
    float var = q4 * (1.f / 192.f) - mu * mu;
    float rstd = rsqrtf(var + 1e-5f);
#pragma unroll
    for (int j = 0; j < 48; j++) {
        int c = c0 + j;
        float vn = (val[j] - mu) * rstd * ln_w[c] + ln_b[c];
        yt[base + (size_t)j * NPIX] = vn;
        float sq = vn * vn;
#pragma unroll
        for (int m = 1; m < 64; m <<= 1) sq += __shfl_xor(sq, m);
        if (pl == 0) atomicAdd(&gxs[b * CI + c], sq);
    }
}

// ---------------------------------------------------------------------------
// K6: GRN (per-channel affine) + out-proj conv1x1 + NCHW store.
// o-groups now wave-uniform (tid>>6) so w_out reads are scalar loads.
__global__ __launch_bounds__(256) void k6_out(
        const float* __restrict__ yt, const float* __restrict__ gxs,
        const float* __restrict__ grn_gamma, const float* __restrict__ grn_beta,
        const float* __restrict__ w_out, float* __restrict__ outp) {
    __shared__ float scale_s[CI];
    __shared__ float beta_s[CI];
    __shared__ float redv[1];
    __shared__ float stage[96 * 16 * 8];
    int blk = blockIdx.x;
    int b = blk >> 7;
    int rest = blk & 127;
    int i0 = (rest >> 4) * 16;
    int t0 = (rest & 15) * 8;
    int tid = threadIdx.x;
    if (tid < CI) scale_s[tid] = sqrtf(gxs[b * CI + tid]);
    __syncthreads();
    if (tid < 64) {
        float p = scale_s[tid] + scale_s[tid + 64] + scale_s[tid + 128];
#pragma unroll
        for (int m = 1; m < 64; m <<= 1) p += __shfl_xor(p, m);
        if (tid == 0) redv[0] = p * (1.f / 192.f);
    }
    __syncthreads();
    float mean = redv[0];
    if (tid < CI) {
        float nx = scale_s[tid] / (mean + 1e-6f);
        scale_s[tid] = 1.f + grn_gamma[tid] * nx;
        beta_s[tid] = grn_beta[tid];
    }
    __syncthreads();

    int og = tid >> 6;          // wave-uniform
    int o0 = og * 24;
    int pg = tid & 63;
    int tt = pg >> 3;           // 8 t-cols
    int ii0 = (pg & 7) * 2;     // 16 i-rows, 2 per lane
    float acc[24][2];
#pragma unroll
    for (int j = 0; j < 24; j++) { acc[j][0] = 0.f; acc[j][1] = 0.f; }
    const float* ybase = yt + ((size_t)b * CI) * NPIX + (t0 + tt) * 128 + (i0 + ii0);
#pragma unroll 2
    for (int cc = 0; cc < CI; cc++) {
        float2 yv = *(const float2*)&ybase[(size_t)cc * NPIX];
        float sc = scale_s[cc], be = beta_s[cc];
        float y0 = yv.x * sc + be, y1 = yv.y * sc + be;
#pragma unroll
        for (int j = 0; j < 24; j++) {
            float wv = w_out[(size_t)(o0 + j) * CI + cc];
            acc[j][0] += wv * y0; acc[j][1] += wv * y1;
        }
    }
#pragma unroll
    for (int j = 0; j < 24; j++) {
        stage[((o0 + j) * 16 + ii0 + 0) * 8 + tt] = acc[j][0];
        stage[((o0 + j) * 16 + ii0 + 1) * 8 + tt] = acc[j][1];
    }
    __syncthreads();
    for (int k = 0; k < 48; k++) {
        int L = k * 256 + tid;
        int o = L >> 7;
        int r = L & 127;
        int ii = r >> 3, t2 = r & 7;
        outp[((size_t)(b * CM + o)) * NPIX + (i0 + ii) * 128 + (t0 + t2)] = stage[L];
    }
}

// ---------------------------------------------------------------------------
extern "C" void kernel_launch(void* const* d_in, const int* in_sizes, int n_in,
                              void* d_out, int out_size, void* d_ws, size_t ws_size,
                              hipStream_t stream) {
    const float* x        = (const float*)d_in[0];
    const float* w_in     = (const float*)d_in[1];
    const float* w_dw     = (const float*)d_in[2];
    const float* b_dw     = (const float*)d_in[3];
    const float* w_xdown  = (const float*)d_in[4];
    const float* w_wup    = (const float*)d_in[5];
    const float* w_lup    = (const float*)d_in[6];
    const float* w_uup    = (const float*)d_in[7];
    const float* w_ddown  = (const float*)d_in[8];
    const float* w_m      = (const float*)d_in[9];
    const float* grn_gamma= (const float*)d_in[10];
    const float* grn_beta = (const float*)d_in[11];
    const float* ln_w     = (const float*)d_in[12];
    const float* ln_b     = (const float*)d_in[13];
    const float* w_out    = (const float*)d_in[14];
    float* ws    = (float*)d_ws;
    float* x1pre = ws + OFF_X1PRE;
    float* x1    = ws + OFF_X1;
    float* x1T   = ws + OFF_X1T;
    float* xp    = ws + OFF_XP;
    float* ypA   = ws + OFF_YPA;
    float* ypB   = ws + OFF_YPB;
    float* yt    = ws + OFF_YT;
    float* gxs   = ws + OFF_GXS;
    float* outp  = (float*)d_out;

    hipMemsetAsync(gxs, 0, BB * CI * sizeof(float), stream);
    dim3 g1(256, 6);
    k1_conv_in<<<g1, 256, 0, stream>>>(x, w_in, x1pre);
    k2_dwconv<<<BB * CI * 4, 256, 0, stream>>>(x1pre, w_dw, b_dw, x1, x1T);
    k3_xp<<<BB * 128, 256, 0, stream>>>(x1, w_xdown, xp);
    k4_scan<<<BB * CI * 2, 256, 0, stream>>>(x1, x1T, xp, w_wup, w_lup, w_uup,
                                             w_ddown, w_m, ypA, ypB);
    k5_ln<<<BB * 256, 256, 0, stream>>>(ypA, ypB, ln_w, ln_b, yt, gxs);
    k6_out<<<256, 256, 0, stream>>>(yt, gxs, grn_gamma, grn_beta, w_out, outp);
}

// Round 4
// 438.863 us; speedup vs baseline: 1.2388x; 1.2388x over previous
//
#include <hip/hip_runtime.h>

// Problem constants
constexpr int BB = 2;        // batch
constexpr int CM = 96;       // d_model
constexpr int CI = 192;      // d_inner
constexpr int NPIX = 128 * 128;   // 16384
constexpr int DS = 16;            // d_state
constexpr int DC = 4 * CI;        // 768

// workspace layout (floats). Reuse: ypB overlays x1pre (dead after K2),
// yt overlays x1 (dead after K4). Total = 25,690,496 floats ~= 103 MB.
constexpr size_t OFF_X1PRE = 0;
constexpr size_t OFF_X1    = 6291456;
constexpr size_t OFF_X1T   = 12582912;
constexpr size_t OFF_XP    = 18874368;
constexpr size_t OFF_YPA   = 19398656;
constexpr size_t OFF_YPB   = 0;          // alias x1pre
constexpr size_t OFF_YT    = 6291456;    // alias x1
constexpr size_t OFF_GXS   = 25690112;

__device__ __forceinline__ float frcp(float x) { return __builtin_amdgcn_rcpf(x); }
__device__ __forceinline__ float sigm(float x) { return frcp(1.f + __expf(-x)); }

// ---------------------------------------------------------------------------
// K1: x1_pre = conv1x1(x, w_in)   (B,96,H,W) -> (B,192,H,W)
__global__ __launch_bounds__(256) void k1_conv_in(const float* __restrict__ x,
                                                  const float* __restrict__ w_in,
                                                  float* __restrict__ x1pre) {
    __shared__ float xs[16][128];
    __shared__ float wsh[16][32];
    int pt = blockIdx.x;
    int b = pt >> 7;
    int pxb = (pt & 127) * 128;
    int cb = blockIdx.y * 32;
    int tid = threadIdx.x;
    int cl0 = (tid >> 5) * 4;
    int px0 = (tid & 31) * 4;
    float acc[4][4];
#pragma unroll
    for (int i = 0; i < 4; i++)
#pragma unroll
        for (int j = 0; j < 4; j++) acc[i][j] = 0.f;

    for (int m0 = 0; m0 < 96; m0 += 16) {
        {
            int e = tid * 8;
            int ml = e >> 7, pp = e & 127;
            const float* src = &x[((size_t)(b * CM + m0 + ml)) * NPIX + pxb + pp];
            float4 v0 = *(const float4*)(src);
            float4 v1 = *(const float4*)(src + 4);
            *(float4*)&xs[ml][pp] = v0;
            *(float4*)&xs[ml][pp + 4] = v1;
        }
        if (tid < 128) {
            int cl = tid >> 2, mq = (tid & 3) * 4;
            float4 v = *(const float4*)&w_in[(size_t)(cb + cl) * CM + m0 + mq];
            wsh[mq + 0][cl] = v.x; wsh[mq + 1][cl] = v.y;
            wsh[mq + 2][cl] = v.z; wsh[mq + 3][cl] = v.w;
        }
        __syncthreads();
#pragma unroll
        for (int m = 0; m < 16; m++) {
            float4 wv = *(const float4*)&wsh[m][cl0];
            float4 xv = *(const float4*)&xs[m][px0];
            float wr[4] = {wv.x, wv.y, wv.z, wv.w};
            float xr[4] = {xv.x, xv.y, xv.z, xv.w};
#pragma unroll
            for (int i = 0; i < 4; i++)
#pragma unroll
                for (int j = 0; j < 4; j++) acc[i][j] += wr[i] * xr[j];
        }
        __syncthreads();
    }
#pragma unroll
    for (int i = 0; i < 4; i++) {
        float4 v = {acc[i][0], acc[i][1], acc[i][2], acc[i][3]};
        *(float4*)&x1pre[((size_t)(b * CI + cb + cl0 + i)) * NPIX + pxb + px0] = v;
    }
}

// ---------------------------------------------------------------------------
// K2: x1 = dwconv3x3(x1_pre)+b, writes BOTH x1 [h][w] and x1T [w][h].
// grid = 384 planes x 4 tiles(64x64); 256 threads.
__global__ __launch_bounds__(256) void k2_dwconv(const float* __restrict__ x1pre,
                                                 const float* __restrict__ w_dw,
                                                 const float* __restrict__ b_dw,
                                                 float* __restrict__ x1,
                                                 float* __restrict__ x1T) {
    __shared__ float inT[66][67];    // 17.7 KB
    __shared__ float outT[64][65];   // 16.6 KB
    int blk = blockIdx.x;
    int bc = blk >> 2;
    int tile = blk & 3;
    int h0 = (tile >> 1) * 64, w0 = (tile & 1) * 64;
    int c = bc % CI;
    const float* src = x1pre + (size_t)bc * NPIX;
    int tid = threadIdx.x;
    for (int idx = tid; idx < 66 * 66; idx += 256) {
        int r = idx / 66, cl = idx - r * 66;
        int hh = h0 - 1 + r, ww = w0 - 1 + cl;
        float v = 0.f;
        if ((unsigned)hh < 128u && (unsigned)ww < 128u) v = src[hh * 128 + ww];
        inT[r][cl] = v;
    }
    float w00 = w_dw[c * 9 + 0], w01 = w_dw[c * 9 + 1], w02 = w_dw[c * 9 + 2];
    float w10 = w_dw[c * 9 + 3], w11 = w_dw[c * 9 + 4], w12 = w_dw[c * 9 + 5];
    float w20 = w_dw[c * 9 + 6], w21 = w_dw[c * 9 + 7], w22 = w_dw[c * 9 + 8];
    float bias = b_dw[c];
    __syncthreads();
    int cl = tid & 63, r0 = tid >> 6;
#pragma unroll 4
    for (int k = 0; k < 16; k++) {
        int r = k * 4 + r0;
        float s = w00 * inT[r][cl]     + w01 * inT[r][cl + 1]     + w02 * inT[r][cl + 2]
                + w10 * inT[r + 1][cl] + w11 * inT[r + 1][cl + 1] + w12 * inT[r + 1][cl + 2]
                + w20 * inT[r + 2][cl] + w21 * inT[r + 2][cl + 1] + w22 * inT[r + 2][cl + 2]
                + bias;
        x1[(size_t)bc * NPIX + (h0 + r) * 128 + w0 + cl] = s;
        outT[r][cl] = s;
    }
    __syncthreads();
#pragma unroll 4
    for (int k = 0; k < 16; k++) {
        int r = k * 4 + r0;
        x1T[(size_t)bc * NPIX + (w0 + r) * 128 + h0 + cl] = outT[cl][r];
    }
}

// ---------------------------------------------------------------------------
// K3: xp = conv1x1(x1, w_xdown) stored TRANSPOSED as (b, w, h, 16)
__global__ __launch_bounds__(256) void k3_xp(const float* __restrict__ x1,
                                             const float* __restrict__ w_xdown,
                                             float* __restrict__ xp) {
    __shared__ float wsh[DS * CI];
    __shared__ float ph[DS][128];
    int blk = blockIdx.x;
    int b = blk >> 7, t = blk & 127;     // t = h-row index
    int tid = threadIdx.x;
    for (int e = tid * 4; e < DS * CI; e += 1024) {
        *(float4*)&wsh[e] = *(const float4*)&w_xdown[e];
    }
    __syncthreads();
    int i = tid & 127;                   // i = w index
    int half = tid >> 7;
    int c0 = half * 96;
    float acc[DS];
#pragma unroll
    for (int s = 0; s < DS; s++) acc[s] = 0.f;
    const float* xbase = x1 + ((size_t)b * CI + c0) * NPIX + t * 128 + i;
#pragma unroll 4
    for (int c = 0; c < 96; c++) {
        float v = xbase[(size_t)c * NPIX];
#pragma unroll
        for (int s = 0; s < DS; s++) acc[s] += wsh[s * CI + c0 + c] * v;
    }
    if (half == 1) {
#pragma unroll
        for (int s = 0; s < DS; s++) ph[s][i] = acc[s];
    }
    __syncthreads();
    if (half == 0) {
        float out[DS];
#pragma unroll
        for (int s = 0; s < DS; s++) out[s] = acc[s] + ph[s][i];
        float4* dst = (float4*)&xp[(((size_t)b * 128 + i) * 128 + t) * DS];
#pragma unroll
        for (int q = 0; q < 4; q++) dst[q] = *(float4*)&out[q * 4];
    }
}

// ---------------------------------------------------------------------------
// K4: fused gate-compute + tridiagonal scan, dir-PAIR per block.
// grid = 768 = (b*CI + c)*2 + parity; parity 0 -> dirs {0,2} (read x1T),
// parity 1 -> dirs {1,3} (read x1). 256 thr = 4 waves: (dir-local dl, half).
// ALL inputs register-prefetched from global (X 2-deep, gates 1-deep);
// LDS only for seam + pair-merge ycol (2 KB). One barrier per step.
__global__ __launch_bounds__(256, 3) void k4_scan(
        const float* __restrict__ x1, const float* __restrict__ x1T,
        const float* __restrict__ xp,
        const float* __restrict__ w_wup, const float* __restrict__ w_lup,
        const float* __restrict__ w_uup, const float* __restrict__ w_ddown,
        const float* __restrict__ w_m,
        float* __restrict__ ypA, float* __restrict__ ypB) {
    __shared__ float ycol[2][2][128];    // 2 KB
    __shared__ float seam[2][2][2];      // [buf][dl][0]=h63, [1]=h64
    int blk = blockIdx.x;
    int parity = blk & 1;
    int bc = blk >> 1;
    int c = bc % CI;
    int b = bc / CI;
    int tid = threadIdx.x;
    int dl = tid >> 7;
    int half = (tid >> 6) & 1;
    int l = tid & 63;
    int i = half * 64 + l;
    int dir = __builtin_amdgcn_readfirstlane(parity + 2 * dl);
    const float* xsrc = (parity ? x1 : x1T) + (size_t)bc * NPIX;
    float* yp = (parity ? ypB : ypA) + (size_t)bc * NPIX;

    int q = dir * CI + c;
    float wm = w_m[dir];
    float wGl[DS], wGm[DS], wGr[DS], wL[DS], wU[DS], wD[DS];
#pragma unroll
    for (int j = 0; j < DS; j++) {
        wGl[j] = w_wup[(size_t)q * DS + j];
        wGm[j] = w_wup[(size_t)(DC + q) * DS + j];
        wGr[j] = w_wup[(size_t)(2 * DC + q) * DS + j];
        wL[j]  = w_lup[(size_t)q * DS + j];
        wU[j]  = w_uup[(size_t)q * DS + j] * wm;
        wD[j]  = w_ddown[(size_t)q * DS + j] * wm;
    }
    if (tid < 8) ((float*)seam)[tid] = 0.f;
    __syncthreads();

    // per-thread gate base: xp layout (b, w, h, 16); this thread's h = i
    const float* xpb = xp + ((size_t)b * 128 * 128 + i) * DS;
    // X row address for scan step t (direction-resolved)
    auto xaddr = [&](int t) {
        int tt = dl ? (127 - t) : t;
        return xsrc + tt * 128 + i;
    };

    // prefetch pipeline: gates 1-deep, X 2-deep
    float4 g0, g1, g2, g3;
    {
        const float4* p = (const float4*)xpb;          // t = 0
        g0 = p[0]; g1 = p[1]; g2 = p[2]; g3 = p[3];
    }
    float Xc = *xaddr(0);
    float Xn = *xaddr(1);

    float h = 0.f;
    for (int t = 0; t < 128; t++) {
        int buf = t & 1;
        // issue next-step prefetches first (latency hidden under this step)
        float4 n0, n1, n2, n3;
        float Xn2 = 0.f;
        if (t < 127) {
            const float4* p = (const float4*)(xpb + (size_t)(t + 1) * 2048);
            n0 = p[0]; n1 = p[1]; n2 = p[2]; n3 = p[3];
        }
        if (t < 126) Xn2 = *xaddr(t + 2);

        float xv[DS] = {g0.x, g0.y, g0.z, g0.w, g1.x, g1.y, g1.z, g1.w,
                        g2.x, g2.y, g2.z, g2.w, g3.x, g3.y, g3.z, g3.w};
        float aGl = 0.f, aGm = 0.f, aGr = 0.f, aL = 0.f, aU = 0.f, aD = 0.f;
#pragma unroll
        for (int j = 0; j < DS; j++) {
            float xa = xv[j];
            aGl += wGl[j] * xa; aGm += wGm[j] * xa; aGr += wGr[j] * xa;
            aL  += wL[j] * xa;  aU  += wU[j] * xa;  aD  += wD[j] * xa;
        }
        float gl = sigm(aGl), gm = sigm(aGm), gr = sigm(aGr);
        float ss = (i == 0) ? (gm + gr) : (i == 127) ? (gl + gm) : (gl + gm + gr);
        float inv = frcp(fmaxf(ss, 1e-7f));
        float up = __shfl_up(h, 1);
        if (l == 0) up = half ? seam[buf ^ 1][dl][0] : 0.f;
        float dn = __shfl_down(h, 1);
        if (l == 63) dn = half ? 0.f : seam[buf ^ 1][dl][1];
        float X = Xc;
        h = aL * X + inv * (gl * up + gm * h + gr * dn);
        ycol[buf][dl][i] = h * aU + X * aD;
        if (half == 0 && l == 63) seam[buf][dl][0] = h;
        if (half == 1 && l == 0)  seam[buf][dl][1] = h;
        __syncthreads();
        if (tid < 128) {
            yp[t * 128 + tid] = ycol[buf][0][tid] + ycol[buf][1][tid];
        }
        // rotate pipeline
        g0 = n0; g1 = n1; g2 = n2; g3 = n3;
        Xc = Xn; Xn = Xn2;
    }
}

// ---------------------------------------------------------------------------
// K5: merge dir-pair partials + LayerNorm over channels -> yt, + per-(b,c) ssq
__global__ __launch_bounds__(256) void k5_ln(const float* __restrict__ ypA,
                                             const float* __restrict__ ypB,
                                             const float* __restrict__ ln_w,
                                             const float* __restrict__ ln_b,
                                             float* __restrict__ yt,
                                             float* __restrict__ gxs) {
    __shared__ float red[8][64];
    int blk = blockIdx.x;
    int b = blk >> 8;
    int pxb = (blk & 255) * 64;
    int tid = threadIdx.x;
    int pl = tid & 63, cp = tid >> 6;
    int c0 = cp * 48;
    size_t base = ((size_t)b * CI + c0) * NPIX + pxb + pl;
    float val[48];
    float sum = 0.f, ssq = 0.f;
#pragma unroll
    for (int j = 0; j < 48; j++) {
        float v = ypA[base + (size_t)j * NPIX] + ypB[base + (size_t)j * NPIX];
        val[j] = v;
        sum += v; ssq += v * v;
    }
    red[cp][pl] = sum; red[4 + cp][pl] = ssq;
    __syncthreads();
    float s4 = red[0][pl] + red[1][pl] + red[2][pl] + red[3][pl];
    float q4 = red[4][pl] + red[5][pl] + red[6][pl] + red[7][pl];
    float mu = s4 * (1.f / 192.f);
    float var = q4 * (1.f / 192.f) - mu * mu;
    float rstd = rsqrtf(var + 1e-5f);
#pragma unroll
    for (int j = 0; j < 48; j++) {
        int c = c0 + j;
        float vn = (val[j] - mu) * rstd * ln_w[c] + ln_b[c];
        yt[base + (size_t)j * NPIX] = vn;
        float sq = vn * vn;
#pragma unroll
        for (int m = 1; m < 64; m <<= 1) sq += __shfl_xor(sq, m);
        if (pl == 0) atomicAdd(&gxs[b * CI + c], sq);
    }
}

// ---------------------------------------------------------------------------
// K6: GRN (per-channel affine) + out-proj conv1x1 + NCHW store.
__global__ __launch_bounds__(256) void k6_out(
        const float* __restrict__ yt, const float* __restrict__ gxs,
        const float* __restrict__ grn_gamma, const float* __restrict__ grn_beta,
        const float* __restrict__ w_out, float* __restrict__ outp) {
    __shared__ float scale_s[CI];
    __shared__ float beta_s[CI];
    __shared__ float redv[1];
    __shared__ float stage[96 * 16 * 8];
    int blk = blockIdx.x;
    int b = blk >> 7;
    int rest = blk & 127;
    int i0 = (rest >> 4) * 16;
    int t0 = (rest & 15) * 8;
    int tid = threadIdx.x;
    if (tid < CI) scale_s[tid] = sqrtf(gxs[b * CI + tid]);
    __syncthreads();
    if (tid < 64) {
        float p = scale_s[tid] + scale_s[tid + 64] + scale_s[tid + 128];
#pragma unroll
        for (int m = 1; m < 64; m <<= 1) p += __shfl_xor(p, m);
        if (tid == 0) redv[0] = p * (1.f / 192.f);
    }
    __syncthreads();
    float mean = redv[0];
    if (tid < CI) {
        float nx = scale_s[tid] / (mean + 1e-6f);
        scale_s[tid] = 1.f + grn_gamma[tid] * nx;
        beta_s[tid] = grn_beta[tid];
    }
    __syncthreads();

    int og = tid >> 6;          // wave-uniform
    int o0 = og * 24;
    int pg = tid & 63;
    int tt = pg >> 3;           // 8 t-cols
    int ii0 = (pg & 7) * 2;     // 16 i-rows, 2 per lane
    float acc[24][2];
#pragma unroll
    for (int j = 0; j < 24; j++) { acc[j][0] = 0.f; acc[j][1] = 0.f; }
    const float* ybase = yt + ((size_t)b * CI) * NPIX + (t0 + tt) * 128 + (i0 + ii0);
#pragma unroll 2
    for (int cc = 0; cc < CI; cc++) {
        float2 yv = *(const float2*)&ybase[(size_t)cc * NPIX];
        float sc = scale_s[cc], be = beta_s[cc];
        float y0 = yv.x * sc + be, y1 = yv.y * sc + be;
#pragma unroll
        for (int j = 0; j < 24; j++) {
            float wv = w_out[(size_t)(o0 + j) * CI + cc];
            acc[j][0] += wv * y0; acc[j][1] += wv * y1;
        }
    }
#pragma unroll
    for (int j = 0; j < 24; j++) {
        stage[((o0 + j) * 16 + ii0 + 0) * 8 + tt] = acc[j][0];
        stage[((o0 + j) * 16 + ii0 + 1) * 8 + tt] = acc[j][1];
    }
    __syncthreads();
    for (int k = 0; k < 48; k++) {
        int L = k * 256 + tid;
        int o = L >> 7;
        int r = L & 127;
        int ii = r >> 3, t2 = r & 7;
        outp[((size_t)(b * CM + o)) * NPIX + (i0 + ii) * 128 + (t0 + t2)] = stage[L];
    }
}

// ---------------------------------------------------------------------------
extern "C" void kernel_launch(void* const* d_in, const int* in_sizes, int n_in,
                              void* d_out, int out_size, void* d_ws, size_t ws_size,
                              hipStream_t stream) {
    const float* x        = (const float*)d_in[0];
    const float* w_in     = (const float*)d_in[1];
    const float* w_dw     = (const float*)d_in[2];
    const float* b_dw     = (const float*)d_in[3];
    const float* w_xdown  = (const float*)d_in[4];
    const float* w_wup    = (const float*)d_in[5];
    const float* w_lup    = (const float*)d_in[6];
    const float* w_uup    = (const float*)d_in[7];
    const float* w_ddown  = (const float*)d_in[8];
    const float* w_m      = (const float*)d_in[9];
    const float* grn_gamma= (const float*)d_in[10];
    const float* grn_beta = (const float*)d_in[11];
    const float* ln_w     = (const float*)d_in[12];
    const float* ln_b     = (const float*)d_in[13];
    const float* w_out    = (const float*)d_in[14];
    float* ws    = (float*)d_ws;
    float* x1pre = ws + OFF_X1PRE;
    float* x1    = ws + OFF_X1;
    float* x1T   = ws + OFF_X1T;
    float* xp    = ws + OFF_XP;
    float* ypA   = ws + OFF_YPA;
    float* ypB   = ws + OFF_YPB;
    float* yt    = ws + OFF_YT;
    float* gxs   = ws + OFF_GXS;
    float* outp  = (float*)d_out;

    hipMemsetAsync(gxs, 0, BB * CI * sizeof(float), stream);
    dim3 g1(256, 6);
    k1_conv_in<<<g1, 256, 0, stream>>>(x, w_in, x1pre);
    k2_dwconv<<<BB * CI * 4, 256, 0, stream>>>(x1pre, w_dw, b_dw, x1, x1T);
    k3_xp<<<BB * 128, 256, 0, stream>>>(x1, w_xdown, xp);
    k4_scan<<<BB * CI * 2, 256, 0, stream>>>(x1, x1T, xp, w_wup, w_lup, w_uup,
                                             w_ddown, w_m, ypA, ypB);
    k5_ln<<<BB * 256, 256, 0, stream>>>(ypA, ypB, ln_w, ln_b, yt, gxs);
    k6_out<<<256, 256, 0, stream>>>(yt, gxs, grn_gamma, grn_beta, w_out, outp);
}